// Round 2
// baseline (30648.315 us; speedup 1.0000x reference)
//
#include <hip/hip_runtime.h>
#include <cmath>

namespace {
constexpr int Dc = 128, Hc = 8, FFc = 512, HIDc = 512;
}

struct Params {
  const float *coords, *Wi, *bi, *W_ph;
  const float *Wq, *Wk, *Wv, *Wo, *g1, *b1, *fW1, *fb1, *fW2, *fb2, *g2, *b2;
  const float *W_node, *W_fixed, *W_step, *W_out, *Wc1, *bc1, *Wc2, *bc2;
  float* out;
};

// Persistent device-global state (re-initialized by kinit every call).
__device__ float g_bn[120 * 8 * 256];   // BN stat slots, 8-way replicated: [slot][rep][sum(128)|sumsq(128)]
__device__ float g_x[512 * 2560];       // raw embeddings, compacted each step
__device__ float g_t[512 * 2560];       // encoder working buffer
__device__ float g_crd[512 * 40];
__device__ int   g_idx[512 * 20];
__device__ float g_state[512 * 8];      // prev(2), first(2), cost(1)
__device__ float g_ctxq[128];           // W_ph @ W_step (step-invariant)
__device__ float g_cctx[512];           // bc1 + W_ph @ Wc1[128:384] (step-invariant)

__device__ __forceinline__ void bn_coef(int slot, const float* g, const float* bb, float cnt,
                                        float* s_scale, float* s_shift, int tid) {
  if (tid < 128) {
    float sm = 0.f, sq = 0.f;
#pragma unroll
    for (int r = 0; r < 8; r++) {
      const float* s = &g_bn[(slot * 8 + r) * 256];
      sm += s[tid]; sq += s[128 + tid];
    }
    float m_ = sm / cnt;
    float v_ = sq / cnt - m_ * m_;
    float rs = rsqrtf(v_ + 1e-5f);
    float sc = rs * g[tid];
    s_scale[tid] = sc;
    s_shift[tid] = bb[tid] - m_ * sc;
  }
}

__global__ __launch_bounds__(256) void kinit(Params p) {
  const int tid = threadIdx.x, b = blockIdx.x;
  for (int i = b * 256 + tid; i < 120 * 8 * 256; i += 512 * 256) g_bn[i] = 0.f;
  for (int e = tid; e < 2560; e += 256) {
    int i = e >> 7, d = e & 127;
    float cx = p.coords[b * 40 + 2 * i], cy = p.coords[b * 40 + 2 * i + 1];
    g_x[b * 2560 + e] = cx * p.Wi[d] + cy * p.Wi[128 + d] + p.bi[d];
  }
  if (tid < 40) g_crd[b * 40 + tid] = p.coords[b * 40 + tid];
  if (tid < 20) g_idx[b * 20 + tid] = tid;
  if (tid < 8) g_state[b * 8 + tid] = 0.f;
  if (b == 0) {
    if (tid < 128) {
      float a = 0.f;
      for (int j = 0; j < 256; j++) a += p.W_ph[j] * p.W_step[j * 128 + tid];
      g_ctxq[tid] = a;
    }
    for (int jj = tid; jj < 512; jj += 256) {
      float a = p.bc1[jj];
      for (int e = 0; e < 256; e++) a += p.W_ph[e] * p.Wc1[(128 + e) * 512 + jj];
      g_cctx[jj] = a;
    }
  }
}

// KA: [apply BN2 of layer l-1 if l>0] -> MHA -> +residual -> write t, BN1 stats.
__global__ __launch_bounds__(256) void ka(Params p, int step, int l) {
  const int tid = threadIdx.x, b = blockIdx.x;
  const int jcol = tid & 127, rhalf = tid >> 7;
  const int n = 20 - step;
  __shared__ float s_t[2560];
  __shared__ float s_U[9280];            // q(2560) | kT(2560) | v(2560) | att(1600)
  __shared__ float s_scale[128], s_shift[128];

  for (int e = tid; e < n * 128; e += 256)
    s_t[e] = (l == 0) ? g_x[b * 2560 + e] : g_t[b * 2560 + e];
  if (l > 0)
    bn_coef(step * 6 + (l - 1) * 2 + 1, p.g2 + (l - 1) * 128, p.b2 + (l - 1) * 128,
            (float)(512 * n), s_scale, s_shift, tid);
  __syncthreads();
  if (l > 0) {
    for (int e = tid; e < n * 128; e += 256) { int d = e & 127; s_t[e] = s_t[e] * s_scale[d] + s_shift[d]; }
    __syncthreads();
  }

  // QKV projection: q,v row-major; k transposed
  {
    const int hh = jcol >> 4, kk = jcol & 15;
    const float* wq = p.Wq + l * 16384 + hh * 2048 + kk;
    const float* wk = p.Wk + l * 16384 + hh * 2048 + kk;
    const float* wv = p.Wv + l * 16384 + hh * 2048 + kk;
    float aq[10], ak[10], av[10];
#pragma unroll
    for (int r = 0; r < 10; r++) { aq[r] = 0.f; ak[r] = 0.f; av[r] = 0.f; }
    for (int d = 0; d < 128; d++) {
      float wqd = wq[d * 16], wkd = wk[d * 16], wvd = wv[d * 16];
#pragma unroll
      for (int r = 0; r < 10; r++) {
        int i = rhalf + 2 * r;
        if (i < n) {
          float tv = s_t[i * 128 + d];
          aq[r] += tv * wqd; ak[r] += tv * wkd; av[r] += tv * wvd;
        }
      }
    }
#pragma unroll
    for (int r = 0; r < 10; r++) {
      int i = rhalf + 2 * r;
      if (i < n) {
        s_U[i * 128 + jcol] = aq[r];
        s_U[2560 + jcol * 20 + i] = ak[r];
        s_U[5120 + i * 128 + jcol] = av[r];
      }
    }
  }
  __syncthreads();
  // attention in 2 chunks of 4 heads; h_out overwrites q columns of finished heads
  for (int hc = 0; hc < 2; hc++) {
    const int tot = 4 * n * n;
    for (int e = tid; e < tot; e += 256) {
      int hh = e / (n * n), rem = e % (n * n), i = rem / n, m = rem % n;
      int head = hc * 4 + hh;
      const float* qr = s_U + i * 128 + head * 16;
      float dacc = 0.f;
#pragma unroll
      for (int k2 = 0; k2 < 16; k2++)
        dacc += qr[k2] * s_U[2560 + (head * 16 + k2) * 20 + m];
      s_U[7680 + hh * 400 + i * 20 + m] = dacc * 0.25f;
    }
    __syncthreads();
    for (int r = tid; r < 4 * n; r += 256) {
      int hh = r / n, i = r % n;
      float* row = s_U + 7680 + hh * 400 + i * 20;
      float mx = row[0];
      for (int m = 1; m < n; m++) mx = fmaxf(mx, row[m]);
      float s = 0.f;
      for (int m = 0; m < n; m++) { float ev = __expf(row[m] - mx); row[m] = ev; s += ev; }
      float inv = 1.f / s;
      for (int m = 0; m < n; m++) row[m] *= inv;
    }
    __syncthreads();
    const int tot2 = 4 * n * 16;
    for (int e = tid; e < tot2; e += 256) {
      int hh = e / (n * 16), rem = e % (n * 16), i = rem / 16, k2 = rem & 15;
      int head = hc * 4 + hh;
      const float* arow = s_U + 7680 + hh * 400 + i * 20;
      float acc = 0.f;
      for (int m = 0; m < n; m++) acc += arow[m] * s_U[5120 + m * 128 + head * 16 + k2];
      s_U[i * 128 + head * 16 + k2] = acc;
    }
    __syncthreads();
  }
  // out-proj + residual; write t; BN1 partial stats
  {
    float acc[10];
#pragma unroll
    for (int r = 0; r < 10; r++) { int i = rhalf + 2 * r; acc[r] = (i < n) ? s_t[i * 128 + jcol] : 0.f; }
    const float* wo = p.Wo + l * 16384 + jcol;
    for (int c = 0; c < 128; c++) {
      float w = wo[c * 128];
#pragma unroll
      for (int r = 0; r < 10; r++) { int i = rhalf + 2 * r; if (i < n) acc[r] += s_U[i * 128 + c] * w; }
    }
    float sm = 0.f, sq = 0.f;
#pragma unroll
    for (int r = 0; r < 10; r++) {
      int i = rhalf + 2 * r;
      if (i < n) { g_t[b * 2560 + i * 128 + jcol] = acc[r]; sm += acc[r]; sq += acc[r] * acc[r]; }
    }
    __syncthreads();
    if (rhalf == 1) { s_scale[jcol] = sm; s_shift[jcol] = sq; }
    __syncthreads();
    if (rhalf == 0) {
      float* slot = &g_bn[((step * 6 + l * 2) * 8 + (b & 7)) * 256];
      atomicAdd(&slot[jcol], sm + s_scale[jcol]);
      atomicAdd(&slot[128 + jcol], sq + s_shift[jcol]);
    }
  }
}

// KB: apply BN1 -> FF (+fb2) -> +residual -> write t, BN2 stats.
__global__ __launch_bounds__(256) void kb(Params p, int step, int l) {
  const int tid = threadIdx.x, b = blockIdx.x;
  const int jcol = tid & 127, rhalf = tid >> 7;
  const int n = 20 - step;
  __shared__ float s_t[2560];
  __shared__ float s_hid[5120];          // 20 x 256 hidden chunk
  __shared__ float s_scale[128], s_shift[128];

  for (int e = tid; e < n * 128; e += 256) s_t[e] = g_t[b * 2560 + e];
  bn_coef(step * 6 + l * 2, p.g1 + l * 128, p.b1 + l * 128, (float)(512 * n), s_scale, s_shift, tid);
  __syncthreads();
  for (int e = tid; e < n * 128; e += 256) { int d = e & 127; s_t[e] = s_t[e] * s_scale[d] + s_shift[d]; }
  __syncthreads();

  float facc[10];
#pragma unroll
  for (int r = 0; r < 10; r++) facc[r] = 0.f;
  for (int chunk = 0; chunk < 2; chunk++) {
    const int hbase = chunk * 256;
    {
      float hacc[20];
      float bias = p.fb1[l * FFc + hbase + tid];
#pragma unroll
      for (int i2 = 0; i2 < 20; i2++) hacc[i2] = bias;
      const float* w1 = p.fW1 + l * Dc * FFc + hbase + tid;
      for (int d = 0; d < 128; d++) {
        float w = w1[d * FFc];
#pragma unroll
        for (int i2 = 0; i2 < 20; i2++) if (i2 < n) hacc[i2] += s_t[i2 * 128 + d] * w;
      }
#pragma unroll
      for (int i2 = 0; i2 < 20; i2++) if (i2 < n) s_hid[i2 * 256 + tid] = fmaxf(hacc[i2], 0.f);
    }
    __syncthreads();
    {
      const float* w2 = p.fW2 + l * FFc * Dc + jcol;
      for (int hp = 0; hp < 256; hp++) {
        float w = w2[(hbase + hp) * 128];
#pragma unroll
        for (int r = 0; r < 10; r++) { int i2 = rhalf + 2 * r; if (i2 < n) facc[r] += s_hid[i2 * 256 + hp] * w; }
      }
    }
    __syncthreads();
  }
  float fb2v = p.fb2[l * 128 + jcol];
  float sm = 0.f, sq = 0.f;
#pragma unroll
  for (int r = 0; r < 10; r++) {
    int i2 = rhalf + 2 * r;
    if (i2 < n) {
      float u = s_t[i2 * 128 + jcol] + facc[r] + fb2v;
      g_t[b * 2560 + i2 * 128 + jcol] = u;
      sm += u; sq += u * u;
    }
  }
  __syncthreads();
  if (rhalf == 1) { s_scale[jcol] = sm; s_shift[jcol] = sq; }
  __syncthreads();
  if (rhalf == 0) {
    float* slot = &g_bn[((step * 6 + l * 2 + 1) * 8 + (b & 7)) * 256];
    atomicAdd(&slot[jcol], sm + s_scale[jcol]);
    atomicAdd(&slot[128 + jcol], sq + s_shift[jcol]);
  }
}

// KD: apply BN2 of layer 2 -> decoder -> outputs -> compaction.
__global__ __launch_bounds__(256) void kd(Params p, int step) {
  const int tid = threadIdx.x, b = blockIdx.x;
  const int n = 20 - step;
  __shared__ float s_t[2560];
  __shared__ float s_U[7840];            // gK(2560) | gV(2560) | lK(2560) | att(160)
  __shared__ float s_scale[128], s_shift[128];
  __shared__ float s_gmean[128], s_qv[128], s_glq[128], s_red[128];
  __shared__ float s_logits[20];
  __shared__ int s_sel;

  for (int e = tid; e < n * 128; e += 256) s_t[e] = g_t[b * 2560 + e];
  bn_coef(step * 6 + 5, p.g2 + 2 * 128, p.b2 + 2 * 128, (float)(512 * n), s_scale, s_shift, tid);
  __syncthreads();
  for (int e = tid; e < n * 128; e += 256) { int d = e & 127; s_t[e] = s_t[e] * s_scale[d] + s_shift[d]; }
  __syncthreads();

  if (tid < 128) {
    float s = 0.f;
    for (int i2 = 0; i2 < n; i2++) s += s_t[i2 * 128 + tid];
    s_gmean[tid] = s / (float)n;
  }
  __syncthreads();
  if (tid < 128) {
    float a = g_ctxq[tid];
    for (int e = 0; e < 128; e++) a += s_gmean[e] * p.W_fixed[e * 128 + tid];
    s_qv[tid] = a;
  }
  // gK | gV | lK = E @ W_node split
  for (int col = tid; col < 384; col += 256) {
    float acc2[20];
#pragma unroll
    for (int i2 = 0; i2 < 20; i2++) acc2[i2] = 0.f;
    const float* wn = p.W_node + col;
    for (int e = 0; e < 128; e++) {
      float w = wn[e * 384];
#pragma unroll
      for (int i2 = 0; i2 < 20; i2++) if (i2 < n) acc2[i2] += s_t[i2 * 128 + e] * w;
    }
    int grp = col >> 7, cc = col & 127;
#pragma unroll
    for (int i2 = 0; i2 < 20; i2++) if (i2 < n) s_U[grp * 2560 + i2 * 128 + cc] = acc2[i2];
  }
  __syncthreads();
  // glimpse attention
  for (int e = tid; e < Hc * n; e += 256) {
    int hh = e / n, m = e % n;
    float dacc = 0.f;
#pragma unroll
    for (int k2 = 0; k2 < 16; k2++) dacc += s_qv[hh * 16 + k2] * s_U[m * 128 + hh * 16 + k2];
    s_U[7680 + hh * 20 + m] = dacc * 0.25f;
  }
  __syncthreads();
  if (tid < Hc) {
    float* row = s_U + 7680 + tid * 20;
    float mx = row[0];
    for (int m = 1; m < n; m++) mx = fmaxf(mx, row[m]);
    float s = 0.f;
    for (int m = 0; m < n; m++) { float ev = __expf(row[m] - mx); row[m] = ev; s += ev; }
    float inv = 1.f / s;
    for (int m = 0; m < n; m++) row[m] *= inv;
  }
  __syncthreads();
  if (tid < 128) {
    int hh = tid >> 4;
    const float* arow = s_U + 7680 + hh * 20;
    float acc = 0.f;
    for (int m = 0; m < n; m++) acc += arow[m] * s_U[2560 + m * 128 + tid];
    s_red[tid] = acc;
  }
  __syncthreads();
  if (tid < 128) {
    float a = 0.f;
    for (int c = 0; c < 128; c++) a += s_red[c] * p.W_out[c * 128 + tid];
    s_glq[tid] = a;
  }
  __syncthreads();
  if (tid < n) {
    const float* lk = s_U + 5120 + tid * 128;
    float dacc = 0.f;
    for (int d = 0; d < 128; d++) dacc += s_glq[d] * lk[d];
    s_logits[tid] = 10.f * tanhf(dacc / 11.313708498984761f);
  }
  __syncthreads();
  if (tid == 0) {
    float mx = s_logits[0]; int sel = 0;
    for (int i2 = 1; i2 < n; i2++) if (s_logits[i2] > mx) { mx = s_logits[i2]; sel = i2; }
    float s = 0.f;
    for (int i2 = 0; i2 < n; i2++) s += __expf(s_logits[i2] - mx);
    p.out[b * 20 + step] = -logf(s);                        // log_p at argmax
    float cx = g_crd[b * 40 + 2 * sel], cy = g_crd[b * 40 + 2 * sel + 1];
    float ir = 0.f;
    if (step > 0) {
      float dx = cx - g_state[b * 8 + 0], dy = cy - g_state[b * 8 + 1];
      float dist = sqrtf(dx * dx + dy * dy);
      ir = -dist;
      g_state[b * 8 + 4] += dist;
    } else { g_state[b * 8 + 2] = cx; g_state[b * 8 + 3] = cy; g_state[b * 8 + 4] = 0.f; }
    p.out[10240 + b * 20 + step] = ir;                      // irs
    p.out[31744 + b * 20 + step] = (float)g_idx[b * 20 + sel]; // tours
    g_state[b * 8 + 0] = cx; g_state[b * 8 + 1] = cy;
    if (step == 19) {
      float dx = g_state[b * 8 + 2] - cx, dy = g_state[b * 8 + 3] - cy;
      float dc = sqrtf(dx * dx + dy * dy);
      p.out[31232 + b] = -dc;                               // reward_final
      p.out[30720 + b] = g_state[b * 8 + 4] + dc;           // cost
    }
    s_sel = sel;
  }
  __syncthreads();
  // critic: h = relu(g_mean @ Wc1_top + c_ctx); val = h @ Wc2 + bc2
  for (int jj = tid; jj < HIDc; jj += 256) {
    float a = g_cctx[jj];
    for (int e = 0; e < 128; e++) a += s_gmean[e] * p.Wc1[e * HIDc + jj];
    s_U[jj] = fmaxf(a, 0.f);
  }
  __syncthreads();
  {
    float pp = s_U[tid] * p.Wc2[tid] + s_U[tid + 256] * p.Wc2[tid + 256];
    if (tid >= 128) s_red[tid - 128] = pp;
    __syncthreads();
    if (tid < 128) s_red[tid] += pp;
    __syncthreads();
#pragma unroll
    for (int sred = 64; sred > 0; sred >>= 1) {
      if (tid < sred) s_red[tid] += s_red[tid + sred];
      __syncthreads();
    }
    if (tid == 0) p.out[20480 + b * 20 + step] = s_red[0] + p.bc2[0]; // vals
  }
  __syncthreads();
  // compact: drop selected row (stable) from x, crd, idx
  if (step < 19) {
    const int sel = s_sel;
    const int movecnt = (n - 1 - sel) * 128;
    float tmp[10]; float crdv = 0.f; int idxv = 0;
#pragma unroll
    for (int r = 0; r < 10; r++) { int e = tid + r * 256; if (e < movecnt) tmp[r] = g_x[b * 2560 + (sel + 1) * 128 + e]; }
    const int mc2 = (n - 1 - sel) * 2;
    if (tid < mc2) crdv = g_crd[b * 40 + (sel + 1) * 2 + tid];
    if (tid < n - 1 - sel) idxv = g_idx[b * 20 + sel + 1 + tid];
    __syncthreads();
#pragma unroll
    for (int r = 0; r < 10; r++) { int e = tid + r * 256; if (e < movecnt) g_x[b * 2560 + sel * 128 + e] = tmp[r]; }
    if (tid < mc2) g_crd[b * 40 + sel * 2 + tid] = crdv;
    if (tid < n - 1 - sel) g_idx[b * 20 + sel + tid] = idxv;
  }
}

extern "C" void kernel_launch(void* const* d_in, const int* in_sizes, int n_in,
                              void* d_out, int out_size, void* d_ws, size_t ws_size,
                              hipStream_t stream) {
  Params p;
  p.coords  = (const float*)d_in[0];
  p.Wi      = (const float*)d_in[1];
  p.bi      = (const float*)d_in[2];
  p.W_ph    = (const float*)d_in[3];
  p.Wq      = (const float*)d_in[4];
  p.Wk      = (const float*)d_in[5];
  p.Wv      = (const float*)d_in[6];
  p.Wo      = (const float*)d_in[7];
  p.g1      = (const float*)d_in[8];
  p.b1      = (const float*)d_in[9];
  p.fW1     = (const float*)d_in[10];
  p.fb1     = (const float*)d_in[11];
  p.fW2     = (const float*)d_in[12];
  p.fb2     = (const float*)d_in[13];
  p.g2      = (const float*)d_in[14];
  p.b2      = (const float*)d_in[15];
  p.W_node  = (const float*)d_in[16];
  p.W_fixed = (const float*)d_in[17];
  p.W_step  = (const float*)d_in[18];
  p.W_out   = (const float*)d_in[19];
  p.Wc1     = (const float*)d_in[20];
  p.bc1     = (const float*)d_in[21];
  p.Wc2     = (const float*)d_in[22];
  p.bc2     = (const float*)d_in[23];
  p.out = (float*)d_out;

  kinit<<<512, 256, 0, stream>>>(p);
  for (int step = 0; step < 20; step++) {
    for (int l = 0; l < 3; l++) {
      ka<<<512, 256, 0, stream>>>(p, step, l);
      kb<<<512, 256, 0, stream>>>(p, step, l);
    }
    kd<<<512, 256, 0, stream>>>(p, step);
  }
}

// Round 3
// 13051.439 us; speedup vs baseline: 2.3483x; 2.3483x over previous
//
#include <hip/hip_runtime.h>
#include <cmath>

namespace {
constexpr int Hc = 8, FFc = 512, HIDc = 512;
}

struct Params {
  const float *coords, *Wi, *bi, *W_ph;
  const float *Wq, *Wk, *Wv, *Wo, *g1, *b1, *fW1, *fb1, *fW2, *fb2, *g2, *b2;
  const float *W_node, *W_fixed, *W_step, *W_out, *Wc1, *bc1, *Wc2, *bc2;
  float* out;
};

// Persistent device-global state (re-initialized every call by kinit).
__device__ __align__(16) float g_bn[120 * 8 * 256]; // BN stats, 8-way replicated [slot][rep][sum|sumsq]
__device__ __align__(16) float g_x[512 * 2560];     // embeddings (compacted each step)
__device__ __align__(16) float g_t[512 * 2560];     // encoder working buffer
__device__ __align__(16) float g_h[512 * 2560];     // attention head outputs (pre out-proj)
__device__ __align__(16) float g_crd[512 * 40];
__device__ int   g_idx[512 * 20];
__device__ float g_state[512 * 8];                  // prev(2), first(2), cost(1)
__device__ __align__(16) float g_ctxq[128];
__device__ __align__(16) float g_cctx[512];
// Transposed weights (thread-column-contiguous for float4 loads)
__device__ __align__(16) float g_WqT[3 * 16384];    // [l][j=h*16+k][d]
__device__ __align__(16) float g_WkT[3 * 16384];
__device__ __align__(16) float g_WvT[3 * 16384];
__device__ __align__(16) float g_WoT[3 * 16384];    // [l][j][c=h*16+k]
__device__ __align__(16) float g_W1T[3 * 65536];    // [l][jj<512][d]
__device__ __align__(16) float g_W2T[3 * 65536];    // [l][j<128][hp<512]
__device__ __align__(16) float g_WnT[384 * 128];    // [col][e]
__device__ __align__(16) float g_WfT[128 * 128];    // [j][e]
__device__ __align__(16) float g_WouT[128 * 128];   // [j][c]
__device__ __align__(16) float g_Wc1T[512 * 128];   // [jj][e<128]

#define DOT4(a, b) ((a).x*(b).x + (a).y*(b).y + (a).z*(b).z + (a).w*(b).w)

__device__ __forceinline__ void bn_coef(int slot, const float* g, const float* bb, float cnt,
                                        float* s_scale, float* s_shift, int tid) {
  if (tid < 128) {
    float sm = 0.f, sq = 0.f;
#pragma unroll
    for (int r = 0; r < 8; r++) {
      const float* s = &g_bn[(slot * 8 + r) * 256];
      sm += s[tid]; sq += s[128 + tid];
    }
    float m_ = sm / cnt;
    float v_ = sq / cnt - m_ * m_;
    float rs = rsqrtf(v_ + 1e-5f);
    float sc = rs * g[tid];
    s_scale[tid] = sc;
    s_shift[tid] = bb[tid] - m_ * sc;
  }
}

__global__ __launch_bounds__(256) void kinit(Params p) {
  const int tid = threadIdx.x, b = blockIdx.x;
  const int gid = b * 256 + tid, GS = 512 * 256;
  for (int i = gid; i < 120 * 8 * 256; i += GS) g_bn[i] = 0.f;
  for (int e = tid; e < 2560; e += 256) {
    int i = e >> 7, d = e & 127;
    float cx = p.coords[b * 40 + 2 * i], cy = p.coords[b * 40 + 2 * i + 1];
    g_x[b * 2560 + e] = cx * p.Wi[d] + cy * p.Wi[128 + d] + p.bi[d];
  }
  if (tid < 40) g_crd[b * 40 + tid] = p.coords[b * 40 + tid];
  if (tid < 20) g_idx[b * 20 + tid] = tid;
  if (tid < 8) g_state[b * 8 + tid] = 0.f;
  if (b == 0) {
    if (tid < 128) {
      float a = 0.f;
      for (int j = 0; j < 256; j++) a += p.W_ph[j] * p.W_step[j * 128 + tid];
      g_ctxq[tid] = a;
    }
    for (int jj = tid; jj < 512; jj += 256) {
      float a = p.bc1[jj];
      for (int e = 0; e < 256; e++) a += p.W_ph[e] * p.Wc1[(128 + e) * 512 + jj];
      g_cctx[jj] = a;
    }
  }
  // transposes
  for (int e = gid; e < 3 * 16384; e += GS) {
    int l = e >> 14, r = e & 16383, j = r >> 7, d = r & 127;
    int src = l * 16384 + (j >> 4) * 2048 + d * 16 + (j & 15);
    g_WqT[e] = p.Wq[src]; g_WkT[e] = p.Wk[src]; g_WvT[e] = p.Wv[src];
  }
  for (int e = gid; e < 3 * 16384; e += GS) {
    int l = e >> 14, r = e & 16383, j = r >> 7, c = r & 127;
    g_WoT[e] = p.Wo[l * 16384 + (c >> 4) * 2048 + (c & 15) * 128 + j];
  }
  for (int e = gid; e < 3 * 65536; e += GS) {
    int l = e >> 16, r = e & 65535, j = r >> 7, d = r & 127;     // j<512
    g_W1T[e] = p.fW1[l * 65536 + d * 512 + j];
  }
  for (int e = gid; e < 3 * 65536; e += GS) {
    int l = e >> 16, r = e & 65535, j = r >> 9, hp = r & 511;    // j<128
    g_W2T[e] = p.fW2[l * 65536 + hp * 128 + j];
  }
  for (int e = gid; e < 384 * 128; e += GS) { int col = e >> 7, ee = e & 127; g_WnT[e] = p.W_node[ee * 384 + col]; }
  for (int e = gid; e < 128 * 128; e += GS) { int j = e >> 7, ee = e & 127; g_WfT[e] = p.W_fixed[ee * 128 + j]; }
  for (int e = gid; e < 128 * 128; e += GS) { int j = e >> 7, c = e & 127; g_WouT[e] = p.W_out[c * 128 + j]; }
  for (int e = gid; e < 512 * 128; e += GS) { int jj = e >> 7, ee = e & 127; g_Wc1T[e] = p.Wc1[ee * 512 + jj]; }
}

// KA1: grid (512, 2=head-half). [BN2(l-1) apply] -> QKV (4 heads) -> softmax -> AV -> g_h.
__global__ __launch_bounds__(256) void ka1(Params p, int step, int l) {
  const int tid = threadIdx.x, b = blockIdx.x, hb = blockIdx.y;
  const int n = 20 - step;
  const int jc = tid & 63, rg = tid >> 6;        // col 0..63 (4 heads), row-group 0..3
  __shared__ __align__(16) float s_t[2560];
  __shared__ __align__(16) float s_q[1280];
  __shared__ float s_kT[1280];                    // [64 cols][20 rows]
  __shared__ __align__(16) float s_v[1280];
  __shared__ float s_att[1600];                   // [4][20][20]
  __shared__ __align__(16) float s_scale[128], s_shift[128];

  if (l > 0)
    bn_coef(step * 6 + (l - 1) * 2 + 1, p.g2 + (l - 1) * 128, p.b2 + (l - 1) * 128,
            (float)(512 * n), s_scale, s_shift, tid);
  __syncthreads();
  const float4* src4 = (const float4*)((l == 0 ? g_x : g_t) + b * 2560);
  float4* st4 = (float4*)s_t;
  for (int e4 = tid; e4 < n * 32; e4 += 256) {
    float4 x = src4[e4];
    if (l > 0) {
      float4 sc = ((const float4*)s_scale)[e4 & 31];
      float4 sh = ((const float4*)s_shift)[e4 & 31];
      x.x = x.x * sc.x + sh.x; x.y = x.y * sc.y + sh.y;
      x.z = x.z * sc.z + sh.z; x.w = x.w * sc.w + sh.w;
    }
    st4[e4] = x;
  }
  __syncthreads();
  {
    const int j = hb * 64 + jc;
    const float4* wq4 = (const float4*)(g_WqT + l * 16384 + j * 128);
    const float4* wk4 = (const float4*)(g_WkT + l * 16384 + j * 128);
    const float4* wv4 = (const float4*)(g_WvT + l * 16384 + j * 128);
    float aq[5], ak[5], av[5];
#pragma unroll
    for (int r = 0; r < 5; r++) { aq[r] = 0.f; ak[r] = 0.f; av[r] = 0.f; }
    for (int d4 = 0; d4 < 32; d4++) {
      float4 wq = wq4[d4], wk = wk4[d4], wv = wv4[d4];
#pragma unroll
      for (int r = 0; r < 5; r++) {
        int i = rg + 4 * r;
        if (i < n) {
          float4 x = st4[i * 32 + d4];
          aq[r] += DOT4(x, wq); ak[r] += DOT4(x, wk); av[r] += DOT4(x, wv);
        }
      }
    }
#pragma unroll
    for (int r = 0; r < 5; r++) {
      int i = rg + 4 * r;
      if (i < n) {
        s_q[i * 64 + jc] = aq[r];
        s_kT[jc * 20 + i] = ak[r];
        s_v[i * 64 + jc] = av[r];
      }
    }
  }
  __syncthreads();
  const int nn = n * n;
  for (int e = tid; e < 4 * nn; e += 256) {
    int hl = e / nn, rem = e % nn, i = rem / n, m = rem % n;
    float dacc = 0.f;
#pragma unroll
    for (int k2 = 0; k2 < 16; k2++)
      dacc += s_q[i * 64 + hl * 16 + k2] * s_kT[(hl * 16 + k2) * 20 + m];
    s_att[hl * 400 + i * 20 + m] = dacc * 0.25f;
  }
  __syncthreads();
  for (int r = tid; r < 4 * n; r += 256) {
    int hl = r / n, i = r % n;
    float* row = s_att + hl * 400 + i * 20;
    float mx = row[0];
    for (int m = 1; m < n; m++) mx = fmaxf(mx, row[m]);
    float s = 0.f;
    for (int m = 0; m < n; m++) { float ev = __expf(row[m] - mx); row[m] = ev; s += ev; }
    float inv = 1.f / s;
    for (int m = 0; m < n; m++) row[m] *= inv;
  }
  __syncthreads();
  for (int e = tid; e < 4 * n * 16; e += 256) {
    int hl = e / (n * 16), rem = e % (n * 16), i = rem >> 4, k2 = rem & 15;
    const float* arow = s_att + hl * 400 + i * 20;
    float acc = 0.f;
    for (int m = 0; m < n; m++) acc += arow[m] * s_v[m * 64 + hl * 16 + k2];
    g_h[b * 2560 + i * 128 + hb * 64 + hl * 16 + k2] = acc;
  }
}

// KA2: grid (512, 2=row parity). out-proj + residual -> g_t, BN1 stats.
__global__ __launch_bounds__(256) void ka2(Params p, int step, int l) {
  const int tid = threadIdx.x, b = blockIdx.x, s = blockIdx.y;
  const int n = 20 - step;
  const int jcol = tid & 127, rhalf = tid >> 7;
  __shared__ __align__(16) float s_h[2560];
  __shared__ __align__(16) float s_x[2560];
  __shared__ __align__(16) float s_scale[128], s_shift[128];
  __shared__ float s_sm[128], s_sq[128];

  if (l > 0)
    bn_coef(step * 6 + (l - 1) * 2 + 1, p.g2 + (l - 1) * 128, p.b2 + (l - 1) * 128,
            (float)(512 * n), s_scale, s_shift, tid);
  __syncthreads();
  const float4* src4 = (const float4*)((l == 0 ? g_x : g_t) + b * 2560);
  const float4* gh4 = (const float4*)(g_h + b * 2560);
  float4* sh4 = (float4*)s_h;
  float4* sx4 = (float4*)s_x;
  for (int e4 = tid; e4 < n * 32; e4 += 256) {
    int i = e4 >> 5;
    if (((i ^ s) & 1) == 0) {
      sh4[e4] = gh4[e4];
      float4 x = src4[e4];
      if (l > 0) {
        float4 sc = ((const float4*)s_scale)[e4 & 31];
        float4 sf = ((const float4*)s_shift)[e4 & 31];
        x.x = x.x * sc.x + sf.x; x.y = x.y * sc.y + sf.y;
        x.z = x.z * sc.z + sf.z; x.w = x.w * sc.w + sf.w;
      }
      sx4[e4] = x;
    }
  }
  __syncthreads();
  float acc[5];
#pragma unroll
  for (int r = 0; r < 5; r++) {
    int i = s + 2 * (rhalf + 2 * r);
    acc[r] = (i < n) ? s_x[i * 128 + jcol] : 0.f;
  }
  const float4* wo4 = (const float4*)(g_WoT + l * 16384 + jcol * 128);
  for (int c4 = 0; c4 < 32; c4++) {
    float4 w = wo4[c4];
#pragma unroll
    for (int r = 0; r < 5; r++) {
      int i = s + 2 * (rhalf + 2 * r);
      if (i < n) { float4 h = sh4[i * 32 + c4]; acc[r] += DOT4(h, w); }
    }
  }
  float sm = 0.f, sq = 0.f;
#pragma unroll
  for (int r = 0; r < 5; r++) {
    int i = s + 2 * (rhalf + 2 * r);
    if (i < n) { g_t[b * 2560 + i * 128 + jcol] = acc[r]; sm += acc[r]; sq += acc[r] * acc[r]; }
  }
  __syncthreads();
  if (rhalf == 1) { s_sm[jcol] = sm; s_sq[jcol] = sq; }
  __syncthreads();
  if (rhalf == 0) {
    float* slot = &g_bn[((step * 6 + l * 2) * 8 + ((b * 2 + s) & 7)) * 256];
    atomicAdd(&slot[jcol], sm + s_sm[jcol]);
    atomicAdd(&slot[128 + jcol], sq + s_sq[jcol]);
  }
}

// KB: grid (512, 2=row parity). BN1 apply -> FF -> residual -> g_t, BN2 stats.
__global__ __launch_bounds__(256) void kb(Params p, int step, int l) {
  const int tid = threadIdx.x, b = blockIdx.x, s = blockIdx.y;
  const int n = 20 - step;
  const int jcol = tid & 127, rhalf = tid >> 7;
  const int nloc = (n - s + 1) >> 1;              // local rows lr -> global i = s + 2*lr
  __shared__ __align__(16) float s_t[1280];       // [10 local rows][128]
  __shared__ __align__(16) float s_hid[2560];     // [10][256] hidden chunk
  __shared__ __align__(16) float s_scale[128], s_shift[128];
  __shared__ float s_sm[128], s_sq[128];

  bn_coef(step * 6 + l * 2, p.g1 + l * 128, p.b1 + l * 128, (float)(512 * n), s_scale, s_shift, tid);
  __syncthreads();
  const float4* src4 = (const float4*)(g_t + b * 2560);
  float4* st4 = (float4*)s_t;
  float4* shid4 = (float4*)s_hid;
  for (int e4 = tid; e4 < nloc * 32; e4 += 256) {
    int lr = e4 >> 5, d4 = e4 & 31;
    float4 x = src4[(s + 2 * lr) * 32 + d4];
    float4 sc = ((const float4*)s_scale)[d4];
    float4 sf = ((const float4*)s_shift)[d4];
    x.x = x.x * sc.x + sf.x; x.y = x.y * sc.y + sf.y;
    x.z = x.z * sc.z + sf.z; x.w = x.w * sc.w + sf.w;
    st4[e4] = x;
  }
  __syncthreads();
  float facc[5];
#pragma unroll
  for (int r = 0; r < 5; r++) facc[r] = 0.f;
  for (int chunk = 0; chunk < 2; chunk++) {
    float hacc[10];
    {
      float bias = p.fb1[l * FFc + chunk * 256 + tid];
#pragma unroll
      for (int lr = 0; lr < 10; lr++) hacc[lr] = bias;
      const float4* w14 = (const float4*)(g_W1T + l * 65536 + (chunk * 256 + tid) * 128);
      for (int d4 = 0; d4 < 32; d4++) {
        float4 w = w14[d4];
#pragma unroll
        for (int lr = 0; lr < 10; lr++)
          if (lr < nloc) { float4 x = st4[lr * 32 + d4]; hacc[lr] += DOT4(x, w); }
      }
    }
    __syncthreads();   // prior chunk's stage-2 readers done with s_hid
#pragma unroll
    for (int lr = 0; lr < 10; lr++)
      if (lr < nloc) s_hid[lr * 256 + tid] = fmaxf(hacc[lr], 0.f);
    __syncthreads();
    {
      const float4* w24 = (const float4*)(g_W2T + l * 65536 + jcol * 512 + chunk * 256);
      for (int h4 = 0; h4 < 64; h4++) {
        float4 w = w24[h4];
#pragma unroll
        for (int r = 0; r < 5; r++) {
          int lr = rhalf + 2 * r;
          if (lr < nloc) { float4 hh = shid4[lr * 64 + h4]; facc[r] += DOT4(hh, w); }
        }
      }
    }
    __syncthreads();
  }
  float fb2v = p.fb2[l * 128 + jcol];
  float sm = 0.f, sq = 0.f;
#pragma unroll
  for (int r = 0; r < 5; r++) {
    int lr = rhalf + 2 * r;
    if (lr < nloc) {
      float u = s_t[lr * 128 + jcol] + facc[r] + fb2v;
      g_t[b * 2560 + (s + 2 * lr) * 128 + jcol] = u;
      sm += u; sq += u * u;
    }
  }
  __syncthreads();
  if (rhalf == 1) { s_sm[jcol] = sm; s_sq[jcol] = sq; }
  __syncthreads();
  if (rhalf == 0) {
    float* slot = &g_bn[((step * 6 + l * 2 + 1) * 8 + ((b * 2 + s) & 7)) * 256];
    atomicAdd(&slot[jcol], sm + s_sm[jcol]);
    atomicAdd(&slot[128 + jcol], sq + s_sq[jcol]);
  }
}

// KD: BN2(l=2) apply -> decoder -> outputs -> compaction. grid 512.
__global__ __launch_bounds__(256) void kd(Params p, int step) {
  const int tid = threadIdx.x, b = blockIdx.x;
  const int n = 20 - step;
  __shared__ __align__(16) float s_t[2560];
  __shared__ __align__(16) float s_U[7840];       // gK(2560)|gV(2560)|lK(2560)|att(160)
  __shared__ __align__(16) float s_scale[128], s_shift[128];
  __shared__ __align__(16) float s_gmean[128];
  __shared__ float s_qv[128], s_glq[128];
  __shared__ __align__(16) float s_red[128];
  __shared__ float s_logits[20];
  __shared__ int s_sel;

  bn_coef(step * 6 + 5, p.g2 + 2 * 128, p.b2 + 2 * 128, (float)(512 * n), s_scale, s_shift, tid);
  __syncthreads();
  const float4* src4 = (const float4*)(g_t + b * 2560);
  float4* st4 = (float4*)s_t;
  for (int e4 = tid; e4 < n * 32; e4 += 256) {
    float4 x = src4[e4];
    float4 sc = ((const float4*)s_scale)[e4 & 31];
    float4 sf = ((const float4*)s_shift)[e4 & 31];
    x.x = x.x * sc.x + sf.x; x.y = x.y * sc.y + sf.y;
    x.z = x.z * sc.z + sf.z; x.w = x.w * sc.w + sf.w;
    st4[e4] = x;
  }
  __syncthreads();
  if (tid < 128) {
    float ssum = 0.f;
    for (int i2 = 0; i2 < n; i2++) ssum += s_t[i2 * 128 + tid];
    s_gmean[tid] = ssum / (float)n;
  }
  __syncthreads();
  if (tid < 128) {
    float a = g_ctxq[tid];
    const float4* wf4 = (const float4*)(g_WfT + tid * 128);
    const float4* gm4 = (const float4*)s_gmean;
    for (int e4 = 0; e4 < 32; e4++) { float4 w = wf4[e4]; float4 g = gm4[e4]; a += DOT4(g, w); }
    s_qv[tid] = a;
  }
  for (int col = tid; col < 384; col += 256) {
    float acc2[20];
#pragma unroll
    for (int i2 = 0; i2 < 20; i2++) acc2[i2] = 0.f;
    const float4* wn4 = (const float4*)(g_WnT + col * 128);
    for (int e4 = 0; e4 < 32; e4++) {
      float4 w = wn4[e4];
#pragma unroll
      for (int i2 = 0; i2 < 20; i2++)
        if (i2 < n) { float4 x = st4[i2 * 32 + e4]; acc2[i2] += DOT4(x, w); }
    }
    int grp = col >> 7, cc = col & 127;
#pragma unroll
    for (int i2 = 0; i2 < 20; i2++) if (i2 < n) s_U[grp * 2560 + i2 * 128 + cc] = acc2[i2];
  }
  __syncthreads();
  for (int e = tid; e < Hc * n; e += 256) {
    int hh = e / n, m = e % n;
    float dacc = 0.f;
#pragma unroll
    for (int k2 = 0; k2 < 16; k2++) dacc += s_qv[hh * 16 + k2] * s_U[m * 128 + hh * 16 + k2];
    s_U[7680 + hh * 20 + m] = dacc * 0.25f;
  }
  __syncthreads();
  if (tid < Hc) {
    float* row = s_U + 7680 + tid * 20;
    float mx = row[0];
    for (int m = 1; m < n; m++) mx = fmaxf(mx, row[m]);
    float s = 0.f;
    for (int m = 0; m < n; m++) { float ev = __expf(row[m] - mx); row[m] = ev; s += ev; }
    float inv = 1.f / s;
    for (int m = 0; m < n; m++) row[m] *= inv;
  }
  __syncthreads();
  if (tid < 128) {
    int hh = tid >> 4;
    const float* arow = s_U + 7680 + hh * 20;
    float acc = 0.f;
    for (int m = 0; m < n; m++) acc += arow[m] * s_U[2560 + m * 128 + tid];
    s_red[tid] = acc;
  }
  __syncthreads();
  if (tid < 128) {
    float a = 0.f;
    const float4* wo4 = (const float4*)(g_WouT + tid * 128);
    const float4* rr4 = (const float4*)s_red;
    for (int c4 = 0; c4 < 32; c4++) { float4 w = wo4[c4]; float4 r = rr4[c4]; a += DOT4(r, w); }
    s_glq[tid] = a;
  }
  __syncthreads();
  if (tid < n) {
    const float* lk = s_U + 5120 + tid * 128;
    float dacc = 0.f;
    for (int d = 0; d < 128; d++) dacc += s_glq[d] * lk[d];
    s_logits[tid] = 10.f * tanhf(dacc / 11.313708498984761f);
  }
  __syncthreads();
  if (tid == 0) {
    float mx = s_logits[0]; int sel = 0;
    for (int i2 = 1; i2 < n; i2++) if (s_logits[i2] > mx) { mx = s_logits[i2]; sel = i2; }
    float s = 0.f;
    for (int i2 = 0; i2 < n; i2++) s += __expf(s_logits[i2] - mx);
    p.out[b * 20 + step] = -logf(s);
    float cx = g_crd[b * 40 + 2 * sel], cy = g_crd[b * 40 + 2 * sel + 1];
    float ir = 0.f;
    if (step > 0) {
      float dx = cx - g_state[b * 8 + 0], dy = cy - g_state[b * 8 + 1];
      float dist = sqrtf(dx * dx + dy * dy);
      ir = -dist;
      g_state[b * 8 + 4] += dist;
    } else { g_state[b * 8 + 2] = cx; g_state[b * 8 + 3] = cy; g_state[b * 8 + 4] = 0.f; }
    p.out[10240 + b * 20 + step] = ir;
    p.out[31744 + b * 20 + step] = (float)g_idx[b * 20 + sel];
    g_state[b * 8 + 0] = cx; g_state[b * 8 + 1] = cy;
    if (step == 19) {
      float dx = g_state[b * 8 + 2] - cx, dy = g_state[b * 8 + 3] - cy;
      float dc = sqrtf(dx * dx + dy * dy);
      p.out[31232 + b] = -dc;
      p.out[30720 + b] = g_state[b * 8 + 4] + dc;
    }
    s_sel = sel;
  }
  __syncthreads();
  for (int jj = tid; jj < HIDc; jj += 256) {
    float a = g_cctx[jj];
    const float4* wc4 = (const float4*)(g_Wc1T + jj * 128);
    const float4* gm4 = (const float4*)s_gmean;
    for (int e4 = 0; e4 < 32; e4++) { float4 w = wc4[e4]; float4 g = gm4[e4]; a += DOT4(g, w); }
    s_U[jj] = fmaxf(a, 0.f);
  }
  __syncthreads();
  {
    float pp = s_U[tid] * p.Wc2[tid] + s_U[tid + 256] * p.Wc2[tid + 256];
    if (tid >= 128) s_red[tid - 128] = pp;
    __syncthreads();
    if (tid < 128) s_red[tid] += pp;
    __syncthreads();
#pragma unroll
    for (int sred = 64; sred > 0; sred >>= 1) {
      if (tid < sred) s_red[tid] += s_red[tid + sred];
      __syncthreads();
    }
    if (tid == 0) p.out[20480 + b * 20 + step] = s_red[0] + p.bc2[0];
  }
  __syncthreads();
  if (step < 19) {
    const int sel = s_sel;
    const int movecnt = (n - 1 - sel) * 128;
    float tmp[10]; float crdv = 0.f; int idxv = 0;
#pragma unroll
    for (int r = 0; r < 10; r++) { int e = tid + r * 256; if (e < movecnt) tmp[r] = g_x[b * 2560 + (sel + 1) * 128 + e]; }
    const int mc2 = (n - 1 - sel) * 2;
    if (tid < mc2) crdv = g_crd[b * 40 + (sel + 1) * 2 + tid];
    if (tid < n - 1 - sel) idxv = g_idx[b * 20 + sel + 1 + tid];
    __syncthreads();
#pragma unroll
    for (int r = 0; r < 10; r++) { int e = tid + r * 256; if (e < movecnt) g_x[b * 2560 + sel * 128 + e] = tmp[r]; }
    if (tid < mc2) g_crd[b * 40 + sel * 2 + tid] = crdv;
    if (tid < n - 1 - sel) g_idx[b * 20 + sel + tid] = idxv;
  }
}

extern "C" void kernel_launch(void* const* d_in, const int* in_sizes, int n_in,
                              void* d_out, int out_size, void* d_ws, size_t ws_size,
                              hipStream_t stream) {
  Params p;
  p.coords  = (const float*)d_in[0];
  p.Wi      = (const float*)d_in[1];
  p.bi      = (const float*)d_in[2];
  p.W_ph    = (const float*)d_in[3];
  p.Wq      = (const float*)d_in[4];
  p.Wk      = (const float*)d_in[5];
  p.Wv      = (const float*)d_in[6];
  p.Wo      = (const float*)d_in[7];
  p.g1      = (const float*)d_in[8];
  p.b1      = (const float*)d_in[9];
  p.fW1     = (const float*)d_in[10];
  p.fb1     = (const float*)d_in[11];
  p.fW2     = (const float*)d_in[12];
  p.fb2     = (const float*)d_in[13];
  p.g2      = (const float*)d_in[14];
  p.b2      = (const float*)d_in[15];
  p.W_node  = (const float*)d_in[16];
  p.W_fixed = (const float*)d_in[17];
  p.W_step  = (const float*)d_in[18];
  p.W_out   = (const float*)d_in[19];
  p.Wc1     = (const float*)d_in[20];
  p.bc1     = (const float*)d_in[21];
  p.Wc2     = (const float*)d_in[22];
  p.bc2     = (const float*)d_in[23];
  p.out = (float*)d_out;

  kinit<<<512, 256, 0, stream>>>(p);
  for (int step = 0; step < 20; step++) {
    for (int l = 0; l < 3; l++) {
      ka1<<<dim3(512, 2), 256, 0, stream>>>(p, step, l);
      ka2<<<dim3(512, 2), 256, 0, stream>>>(p, step, l);
      kb<<<dim3(512, 2), 256, 0, stream>>>(p, step, l);
    }
    kd<<<512, 256, 0, stream>>>(p, step);
  }
}

// Round 4
// 8703.900 us; speedup vs baseline: 3.5212x; 1.4995x over previous
//
#include <hip/hip_runtime.h>
#include <cmath>

namespace {
constexpr int Hc = 8, FFc = 512, HIDc = 512;
}

struct Params {
  const float *coords, *Wi, *bi, *W_ph;
  const float *Wq, *Wk, *Wv, *Wo, *g1, *b1, *fW1, *fb1, *fW2, *fb2, *g2, *b2;
  const float *W_node, *W_fixed, *W_step, *W_out, *Wc1, *bc1, *Wc2, *bc2;
  float* out;
};

// Persistent device-global state (re-initialized every call by kinit).
__device__ __align__(16) float g_bn[120 * 8 * 256]; // BN stats, 8-way replicated
__device__ __align__(16) float g_x[512 * 2560];
__device__ __align__(16) float g_t[512 * 2560];
__device__ __align__(16) float g_h[512 * 2560];
__device__ __align__(16) float g_crd[512 * 40];
__device__ int   g_idx[512 * 20];
__device__ float g_state[512 * 8];
__device__ __align__(16) float g_ctxq[128];
__device__ __align__(16) float g_cctx[512];
// Interleaved-packed weights: float4 at (k4*J + j) holds W[k4*4+0..3][j]
// -> consecutive lanes (j) read consecutive float4s = perfectly coalesced.
__device__ __align__(16) float g_Wqp[3 * 16384];    // [l][d4<32][j<128][4]
__device__ __align__(16) float g_Wkp[3 * 16384];
__device__ __align__(16) float g_Wvp[3 * 16384];
__device__ __align__(16) float g_Wop[3 * 16384];    // [l][c4<32][j<128][4]
__device__ __align__(16) float g_W1p[3 * 65536];    // [l][d4<32][j<512][4]
__device__ __align__(16) float g_W2p[3 * 65536];    // [l][h4<128][j<128][4]
__device__ __align__(16) float g_Wnp[49152];        // [e4<32][col<384][4]
__device__ __align__(16) float g_Wfp[16384];        // [e4<32][j<128][4]
__device__ __align__(16) float g_Woup[16384];       // [c4<32][j<128][4]
__device__ __align__(16) float g_Wc1p[65536];       // [e4<32][jj<512][4]

#define DOT4(a, b) ((a).x*(b).x + (a).y*(b).y + (a).z*(b).z + (a).w*(b).w)

__device__ __forceinline__ void bn_coef(int slot, const float* g, const float* bb, float cnt,
                                        float* s_scale, float* s_shift, int tid) {
  if (tid < 128) {
    float sm = 0.f, sq = 0.f;
#pragma unroll
    for (int r = 0; r < 8; r++) {
      const float* s = &g_bn[(slot * 8 + r) * 256];
      sm += s[tid]; sq += s[128 + tid];
    }
    float m_ = sm / cnt;
    float v_ = sq / cnt - m_ * m_;
    float rs = rsqrtf(v_ + 1e-5f);
    float sc = rs * g[tid];
    s_scale[tid] = sc;
    s_shift[tid] = bb[tid] - m_ * sc;
  }
}

__global__ __launch_bounds__(256) void kinit(Params p) {
  const int tid = threadIdx.x, b = blockIdx.x;
  const int gid = b * 256 + tid, GS = 512 * 256;
  for (int i = gid; i < 120 * 8 * 256; i += GS) g_bn[i] = 0.f;
  for (int e = tid; e < 2560; e += 256) {
    int i = e >> 7, d = e & 127;
    float cx = p.coords[b * 40 + 2 * i], cy = p.coords[b * 40 + 2 * i + 1];
    g_x[b * 2560 + e] = cx * p.Wi[d] + cy * p.Wi[128 + d] + p.bi[d];
  }
  if (tid < 40) g_crd[b * 40 + tid] = p.coords[b * 40 + tid];
  if (tid < 20) g_idx[b * 20 + tid] = tid;
  if (tid < 8) g_state[b * 8 + tid] = 0.f;
  if (b == 0) {
    if (tid < 128) {
      float a = 0.f;
      for (int j = 0; j < 256; j++) a += p.W_ph[j] * p.W_step[j * 128 + tid];
      g_ctxq[tid] = a;
    }
    for (int jj = tid; jj < 512; jj += 256) {
      float a = p.bc1[jj];
      for (int e = 0; e < 256; e++) a += p.W_ph[e] * p.Wc1[(128 + e) * 512 + jj];
      g_cctx[jj] = a;
    }
  }
  // interleaved packs
  for (int e = gid; e < 3 * 16384; e += GS) {
    int sub = e & 3, rest = e >> 2;
    int j = rest & 127, rest2 = rest >> 7, d4 = rest2 & 31, l = rest2 >> 5;
    int d = d4 * 4 + sub;
    int src = l * 16384 + (j >> 4) * 2048 + d * 16 + (j & 15);
    g_Wqp[e] = p.Wq[src]; g_Wkp[e] = p.Wk[src]; g_Wvp[e] = p.Wv[src];
    int c = d;  // reuse decomp for Wo: k4=c4, col=j
    g_Wop[e] = p.Wo[l * 16384 + (c >> 4) * 2048 + (c & 15) * 128 + j];
  }
  for (int e = gid; e < 3 * 65536; e += GS) {
    int sub = e & 3, rest = e >> 2;
    int j = rest & 511, rest2 = rest >> 9, d4 = rest2 & 31, l = rest2 >> 5;
    g_W1p[e] = p.fW1[l * 65536 + (d4 * 4 + sub) * 512 + j];
  }
  for (int e = gid; e < 3 * 65536; e += GS) {
    int sub = e & 3, rest = e >> 2;
    int j = rest & 127, rest2 = rest >> 7, h4 = rest2 & 127, l = rest2 >> 7;
    g_W2p[e] = p.fW2[l * 65536 + (h4 * 4 + sub) * 128 + j];
  }
  for (int e = gid; e < 49152; e += GS) {
    int sub = e & 3, rest = e >> 2;
    int col = rest % 384, e4 = rest / 384;
    g_Wnp[e] = p.W_node[(e4 * 4 + sub) * 384 + col];
  }
  for (int e = gid; e < 16384; e += GS) {
    int sub = e & 3, rest = e >> 2;
    int j = rest & 127, e4 = rest >> 7;
    g_Wfp[e] = p.W_fixed[(e4 * 4 + sub) * 128 + j];
    g_Woup[e] = p.W_out[(e4 * 4 + sub) * 128 + j];
  }
  for (int e = gid; e < 65536; e += GS) {
    int sub = e & 3, rest = e >> 2;
    int jj = rest & 511, e4 = rest >> 9;
    g_Wc1p[e] = p.Wc1[(e4 * 4 + sub) * 512 + jj];
  }
}

// KA1: grid (512, 2=head-half). [BN2(l-1) apply] -> QKV (4 heads) -> softmax -> AV -> g_h.
__global__ __launch_bounds__(256) void ka1(Params p, int step, int l) {
  const int tid = threadIdx.x, b = blockIdx.x, hb = blockIdx.y;
  const int n = 20 - step;
  const int jc = tid & 63, rg = tid >> 6;
  __shared__ __align__(16) float s_t[2560];
  __shared__ __align__(16) float s_q[1280];
  __shared__ float s_kT[1280];
  __shared__ __align__(16) float s_v[1280];
  __shared__ float s_att[1600];
  __shared__ __align__(16) float s_scale[128], s_shift[128];

  if (l > 0)
    bn_coef(step * 6 + (l - 1) * 2 + 1, p.g2 + (l - 1) * 128, p.b2 + (l - 1) * 128,
            (float)(512 * n), s_scale, s_shift, tid);
  __syncthreads();
  const float4* src4 = (const float4*)((l == 0 ? g_x : g_t) + b * 2560);
  float4* st4 = (float4*)s_t;
  for (int e4 = tid; e4 < n * 32; e4 += 256) {
    float4 x = src4[e4];
    if (l > 0) {
      float4 sc = ((const float4*)s_scale)[e4 & 31];
      float4 sh = ((const float4*)s_shift)[e4 & 31];
      x.x = x.x * sc.x + sh.x; x.y = x.y * sc.y + sh.y;
      x.z = x.z * sc.z + sh.z; x.w = x.w * sc.w + sh.w;
    }
    st4[e4] = x;
  }
  __syncthreads();
  {
    const int j = hb * 64 + jc;
    const float4* wq4 = (const float4*)g_Wqp + l * 4096 + j;
    const float4* wk4 = (const float4*)g_Wkp + l * 4096 + j;
    const float4* wv4 = (const float4*)g_Wvp + l * 4096 + j;
    float aq[5], ak[5], av[5];
#pragma unroll
    for (int r = 0; r < 5; r++) { aq[r] = 0.f; ak[r] = 0.f; av[r] = 0.f; }
    for (int d4 = 0; d4 < 32; d4++) {
      float4 wq = wq4[d4 * 128], wk = wk4[d4 * 128], wv = wv4[d4 * 128];
#pragma unroll
      for (int r = 0; r < 5; r++) {
        int i = rg + 4 * r;
        if (i < n) {
          float4 x = st4[i * 32 + d4];
          aq[r] += DOT4(x, wq); ak[r] += DOT4(x, wk); av[r] += DOT4(x, wv);
        }
      }
    }
#pragma unroll
    for (int r = 0; r < 5; r++) {
      int i = rg + 4 * r;
      if (i < n) {
        s_q[i * 64 + jc] = aq[r];
        s_kT[jc * 20 + i] = ak[r];
        s_v[i * 64 + jc] = av[r];
      }
    }
  }
  __syncthreads();
  const int nn = n * n;
  for (int e = tid; e < 4 * nn; e += 256) {
    int hl = e / nn, rem = e % nn, i = rem / n, m = rem % n;
    float dacc = 0.f;
#pragma unroll
    for (int k2 = 0; k2 < 16; k2++)
      dacc += s_q[i * 64 + hl * 16 + k2] * s_kT[(hl * 16 + k2) * 20 + m];
    s_att[hl * 400 + i * 20 + m] = dacc * 0.25f;
  }
  __syncthreads();
  for (int r = tid; r < 4 * n; r += 256) {
    int hl = r / n, i = r % n;
    float* row = s_att + hl * 400 + i * 20;
    float mx = row[0];
    for (int m = 1; m < n; m++) mx = fmaxf(mx, row[m]);
    float s = 0.f;
    for (int m = 0; m < n; m++) { float ev = __expf(row[m] - mx); row[m] = ev; s += ev; }
    float inv = 1.f / s;
    for (int m = 0; m < n; m++) row[m] *= inv;
  }
  __syncthreads();
  for (int e = tid; e < 4 * n * 16; e += 256) {
    int hl = e / (n * 16), rem = e % (n * 16), i = rem >> 4, k2 = rem & 15;
    const float* arow = s_att + hl * 400 + i * 20;
    float acc = 0.f;
    for (int m = 0; m < n; m++) acc += arow[m] * s_v[m * 64 + hl * 16 + k2];
    g_h[b * 2560 + i * 128 + hb * 64 + hl * 16 + k2] = acc;
  }
}

// KA2: grid (512, 2=row parity). out-proj + residual -> g_t, BN1 stats.
__global__ __launch_bounds__(256) void ka2(Params p, int step, int l) {
  const int tid = threadIdx.x, b = blockIdx.x, s = blockIdx.y;
  const int n = 20 - step;
  const int jcol = tid & 127, rhalf = tid >> 7;
  __shared__ __align__(16) float s_h[2560];
  __shared__ __align__(16) float s_x[2560];
  __shared__ __align__(16) float s_scale[128], s_shift[128];
  __shared__ float s_sm[128], s_sq[128];

  if (l > 0)
    bn_coef(step * 6 + (l - 1) * 2 + 1, p.g2 + (l - 1) * 128, p.b2 + (l - 1) * 128,
            (float)(512 * n), s_scale, s_shift, tid);
  __syncthreads();
  const float4* src4 = (const float4*)((l == 0 ? g_x : g_t) + b * 2560);
  const float4* gh4 = (const float4*)(g_h + b * 2560);
  float4* sh4 = (float4*)s_h;
  float4* sx4 = (float4*)s_x;
  for (int e4 = tid; e4 < n * 32; e4 += 256) {
    int i = e4 >> 5;
    if (((i ^ s) & 1) == 0) {
      sh4[e4] = gh4[e4];
      float4 x = src4[e4];
      if (l > 0) {
        float4 sc = ((const float4*)s_scale)[e4 & 31];
        float4 sf = ((const float4*)s_shift)[e4 & 31];
        x.x = x.x * sc.x + sf.x; x.y = x.y * sc.y + sf.y;
        x.z = x.z * sc.z + sf.z; x.w = x.w * sc.w + sf.w;
      }
      sx4[e4] = x;
    }
  }
  __syncthreads();
  float acc[5];
#pragma unroll
  for (int r = 0; r < 5; r++) {
    int i = s + 2 * (rhalf + 2 * r);
    acc[r] = (i < n) ? s_x[i * 128 + jcol] : 0.f;
  }
  const float4* wo4 = (const float4*)g_Wop + l * 4096 + jcol;
  for (int c4 = 0; c4 < 32; c4++) {
    float4 w = wo4[c4 * 128];
#pragma unroll
    for (int r = 0; r < 5; r++) {
      int i = s + 2 * (rhalf + 2 * r);
      if (i < n) { float4 h = sh4[i * 32 + c4]; acc[r] += DOT4(h, w); }
    }
  }
  float sm = 0.f, sq = 0.f;
#pragma unroll
  for (int r = 0; r < 5; r++) {
    int i = s + 2 * (rhalf + 2 * r);
    if (i < n) { g_t[b * 2560 + i * 128 + jcol] = acc[r]; sm += acc[r]; sq += acc[r] * acc[r]; }
  }
  __syncthreads();
  if (rhalf == 1) { s_sm[jcol] = sm; s_sq[jcol] = sq; }
  __syncthreads();
  if (rhalf == 0) {
    float* slot = &g_bn[((step * 6 + l * 2) * 8 + ((b * 2 + s) & 7)) * 256];
    atomicAdd(&slot[jcol], sm + s_sm[jcol]);
    atomicAdd(&slot[128 + jcol], sq + s_sq[jcol]);
  }
}

// KB: grid (512, 2=row parity). BN1 apply -> FF -> residual -> g_t, BN2 stats.
__global__ __launch_bounds__(256) void kb(Params p, int step, int l) {
  const int tid = threadIdx.x, b = blockIdx.x, s = blockIdx.y;
  const int n = 20 - step;
  const int jcol = tid & 127, rhalf = tid >> 7;
  const int nloc = (n - s + 1) >> 1;
  __shared__ __align__(16) float s_t[1280];
  __shared__ __align__(16) float s_hid[2560];
  __shared__ __align__(16) float s_scale[128], s_shift[128];
  __shared__ float s_sm[128], s_sq[128];

  bn_coef(step * 6 + l * 2, p.g1 + l * 128, p.b1 + l * 128, (float)(512 * n), s_scale, s_shift, tid);
  __syncthreads();
  const float4* src4 = (const float4*)(g_t + b * 2560);
  float4* st4 = (float4*)s_t;
  float4* shid4 = (float4*)s_hid;
  for (int e4 = tid; e4 < nloc * 32; e4 += 256) {
    int lr = e4 >> 5, d4 = e4 & 31;
    float4 x = src4[(s + 2 * lr) * 32 + d4];
    float4 sc = ((const float4*)s_scale)[d4];
    float4 sf = ((const float4*)s_shift)[d4];
    x.x = x.x * sc.x + sf.x; x.y = x.y * sc.y + sf.y;
    x.z = x.z * sc.z + sf.z; x.w = x.w * sc.w + sf.w;
    st4[e4] = x;
  }
  __syncthreads();
  float facc[5];
#pragma unroll
  for (int r = 0; r < 5; r++) facc[r] = 0.f;
  for (int chunk = 0; chunk < 2; chunk++) {
    float hacc[10];
    {
      float bias = p.fb1[l * FFc + chunk * 256 + tid];
#pragma unroll
      for (int lr = 0; lr < 10; lr++) hacc[lr] = bias;
      const float4* w14 = (const float4*)g_W1p + l * 16384 + chunk * 256 + tid;
      for (int d4 = 0; d4 < 32; d4++) {
        float4 w = w14[d4 * 512];
#pragma unroll
        for (int lr = 0; lr < 10; lr++)
          if (lr < nloc) { float4 x = st4[lr * 32 + d4]; hacc[lr] += DOT4(x, w); }
      }
    }
    __syncthreads();
#pragma unroll
    for (int lr = 0; lr < 10; lr++)
      if (lr < nloc) s_hid[lr * 256 + tid] = fmaxf(hacc[lr], 0.f);
    __syncthreads();
    {
      const float4* w24 = (const float4*)g_W2p + l * 16384 + chunk * 8192 + jcol;
      for (int h4 = 0; h4 < 64; h4++) {
        float4 w = w24[h4 * 128];
#pragma unroll
        for (int r = 0; r < 5; r++) {
          int lr = rhalf + 2 * r;
          if (lr < nloc) { float4 hh = shid4[lr * 64 + h4]; facc[r] += DOT4(hh, w); }
        }
      }
    }
    __syncthreads();
  }
  float fb2v = p.fb2[l * 128 + jcol];
  float sm = 0.f, sq = 0.f;
#pragma unroll
  for (int r = 0; r < 5; r++) {
    int lr = rhalf + 2 * r;
    if (lr < nloc) {
      float u = s_t[lr * 128 + jcol] + facc[r] + fb2v;
      g_t[b * 2560 + (s + 2 * lr) * 128 + jcol] = u;
      sm += u; sq += u * u;
    }
  }
  __syncthreads();
  if (rhalf == 1) { s_sm[jcol] = sm; s_sq[jcol] = sq; }
  __syncthreads();
  if (rhalf == 0) {
    float* slot = &g_bn[((step * 6 + l * 2 + 1) * 8 + ((b * 2 + s) & 7)) * 256];
    atomicAdd(&slot[jcol], sm + s_sm[jcol]);
    atomicAdd(&slot[128 + jcol], sq + s_sq[jcol]);
  }
}

// KD: BN2(l=2) apply -> decoder -> outputs -> compaction. grid 512.
__global__ __launch_bounds__(256) void kd(Params p, int step) {
  const int tid = threadIdx.x, b = blockIdx.x;
  const int n = 20 - step;
  __shared__ __align__(16) float s_t[2560];
  __shared__ __align__(16) float s_U[7840];
  __shared__ __align__(16) float s_scale[128], s_shift[128];
  __shared__ __align__(16) float s_gmean[128];
  __shared__ float s_qv[128], s_glq[128];
  __shared__ __align__(16) float s_red[128];
  __shared__ float s_logits[20];
  __shared__ int s_sel;

  bn_coef(step * 6 + 5, p.g2 + 2 * 128, p.b2 + 2 * 128, (float)(512 * n), s_scale, s_shift, tid);
  __syncthreads();
  const float4* src4 = (const float4*)(g_t + b * 2560);
  float4* st4 = (float4*)s_t;
  for (int e4 = tid; e4 < n * 32; e4 += 256) {
    float4 x = src4[e4];
    float4 sc = ((const float4*)s_scale)[e4 & 31];
    float4 sf = ((const float4*)s_shift)[e4 & 31];
    x.x = x.x * sc.x + sf.x; x.y = x.y * sc.y + sf.y;
    x.z = x.z * sc.z + sf.z; x.w = x.w * sc.w + sf.w;
    st4[e4] = x;
  }
  __syncthreads();
  if (tid < 128) {
    float ssum = 0.f;
    for (int i2 = 0; i2 < n; i2++) ssum += s_t[i2 * 128 + tid];
    s_gmean[tid] = ssum / (float)n;
  }
  __syncthreads();
  if (tid < 128) {
    float a = g_ctxq[tid];
    const float4* wf4 = (const float4*)g_Wfp + tid;
    const float4* gm4 = (const float4*)s_gmean;
    for (int e4 = 0; e4 < 32; e4++) { float4 w = wf4[e4 * 128]; float4 g = gm4[e4]; a += DOT4(g, w); }
    s_qv[tid] = a;
  }
  for (int col = tid; col < 384; col += 256) {
    float acc2[20];
#pragma unroll
    for (int i2 = 0; i2 < 20; i2++) acc2[i2] = 0.f;
    const float4* wn4 = (const float4*)g_Wnp + col;
    for (int e4 = 0; e4 < 32; e4++) {
      float4 w = wn4[e4 * 384];
#pragma unroll
      for (int i2 = 0; i2 < 20; i2++)
        if (i2 < n) { float4 x = st4[i2 * 32 + e4]; acc2[i2] += DOT4(x, w); }
    }
    int grp = col >> 7, cc = col & 127;
#pragma unroll
    for (int i2 = 0; i2 < 20; i2++) if (i2 < n) s_U[grp * 2560 + i2 * 128 + cc] = acc2[i2];
  }
  __syncthreads();
  for (int e = tid; e < Hc * n; e += 256) {
    int hh = e / n, m = e % n;
    float dacc = 0.f;
#pragma unroll
    for (int k2 = 0; k2 < 16; k2++) dacc += s_qv[hh * 16 + k2] * s_U[m * 128 + hh * 16 + k2];
    s_U[7680 + hh * 20 + m] = dacc * 0.25f;
  }
  __syncthreads();
  if (tid < Hc) {
    float* row = s_U + 7680 + tid * 20;
    float mx = row[0];
    for (int m = 1; m < n; m++) mx = fmaxf(mx, row[m]);
    float s = 0.f;
    for (int m = 0; m < n; m++) { float ev = __expf(row[m] - mx); row[m] = ev; s += ev; }
    float inv = 1.f / s;
    for (int m = 0; m < n; m++) row[m] *= inv;
  }
  __syncthreads();
  if (tid < 128) {
    int hh = tid >> 4;
    const float* arow = s_U + 7680 + hh * 20;
    float acc = 0.f;
    for (int m = 0; m < n; m++) acc += arow[m] * s_U[2560 + m * 128 + tid];
    s_red[tid] = acc;
  }
  __syncthreads();
  if (tid < 128) {
    float a = 0.f;
    const float4* wo4 = (const float4*)g_Woup + tid;
    const float4* rr4 = (const float4*)s_red;
    for (int c4 = 0; c4 < 32; c4++) { float4 w = wo4[c4 * 128]; float4 r = rr4[c4]; a += DOT4(r, w); }
    s_glq[tid] = a;
  }
  __syncthreads();
  if (tid < n) {
    const float* lk = s_U + 5120 + tid * 128;
    float dacc = 0.f;
    for (int d = 0; d < 128; d++) dacc += s_glq[d] * lk[d];
    s_logits[tid] = 10.f * tanhf(dacc / 11.313708498984761f);
  }
  __syncthreads();
  if (tid == 0) {
    float mx = s_logits[0]; int sel = 0;
    for (int i2 = 1; i2 < n; i2++) if (s_logits[i2] > mx) { mx = s_logits[i2]; sel = i2; }
    float s = 0.f;
    for (int i2 = 0; i2 < n; i2++) s += __expf(s_logits[i2] - mx);
    p.out[b * 20 + step] = -logf(s);
    float cx = g_crd[b * 40 + 2 * sel], cy = g_crd[b * 40 + 2 * sel + 1];
    float ir = 0.f;
    if (step > 0) {
      float dx = cx - g_state[b * 8 + 0], dy = cy - g_state[b * 8 + 1];
      float dist = sqrtf(dx * dx + dy * dy);
      ir = -dist;
      g_state[b * 8 + 4] += dist;
    } else { g_state[b * 8 + 2] = cx; g_state[b * 8 + 3] = cy; g_state[b * 8 + 4] = 0.f; }
    p.out[10240 + b * 20 + step] = ir;
    p.out[31744 + b * 20 + step] = (float)g_idx[b * 20 + sel];
    g_state[b * 8 + 0] = cx; g_state[b * 8 + 1] = cy;
    if (step == 19) {
      float dx = g_state[b * 8 + 2] - cx, dy = g_state[b * 8 + 3] - cy;
      float dc = sqrtf(dx * dx + dy * dy);
      p.out[31232 + b] = -dc;
      p.out[30720 + b] = g_state[b * 8 + 4] + dc;
    }
    s_sel = sel;
  }
  __syncthreads();
  for (int jj = tid; jj < HIDc; jj += 256) {
    float a = g_cctx[jj];
    const float4* wc4 = (const float4*)g_Wc1p + jj;
    const float4* gm4 = (const float4*)s_gmean;
    for (int e4 = 0; e4 < 32; e4++) { float4 w = wc4[e4 * 512]; float4 g = gm4[e4]; a += DOT4(g, w); }
    s_U[jj] = fmaxf(a, 0.f);
  }
  __syncthreads();
  {
    float pp = s_U[tid] * p.Wc2[tid] + s_U[tid + 256] * p.Wc2[tid + 256];
    if (tid >= 128) s_red[tid - 128] = pp;
    __syncthreads();
    if (tid < 128) s_red[tid] += pp;
    __syncthreads();
#pragma unroll
    for (int sred = 64; sred > 0; sred >>= 1) {
      if (tid < sred) s_red[tid] += s_red[tid + sred];
      __syncthreads();
    }
    if (tid == 0) p.out[20480 + b * 20 + step] = s_red[0] + p.bc2[0];
  }
  __syncthreads();
  if (step < 19) {
    const int sel = s_sel;
    const int movecnt = (n - 1 - sel) * 128;
    float tmp[10]; float crdv = 0.f; int idxv = 0;
#pragma unroll
    for (int r = 0; r < 10; r++) { int e = tid + r * 256; if (e < movecnt) tmp[r] = g_x[b * 2560 + (sel + 1) * 128 + e]; }
    const int mc2 = (n - 1 - sel) * 2;
    if (tid < mc2) crdv = g_crd[b * 40 + (sel + 1) * 2 + tid];
    if (tid < n - 1 - sel) idxv = g_idx[b * 20 + sel + 1 + tid];
    __syncthreads();
#pragma unroll
    for (int r = 0; r < 10; r++) { int e = tid + r * 256; if (e < movecnt) g_x[b * 2560 + sel * 128 + e] = tmp[r]; }
    if (tid < mc2) g_crd[b * 40 + sel * 2 + tid] = crdv;
    if (tid < n - 1 - sel) g_idx[b * 20 + sel + tid] = idxv;
  }
}

extern "C" void kernel_launch(void* const* d_in, const int* in_sizes, int n_in,
                              void* d_out, int out_size, void* d_ws, size_t ws_size,
                              hipStream_t stream) {
  Params p;
  p.coords  = (const float*)d_in[0];
  p.Wi      = (const float*)d_in[1];
  p.bi      = (const float*)d_in[2];
  p.W_ph    = (const float*)d_in[3];
  p.Wq      = (const float*)d_in[4];
  p.Wk      = (const float*)d_in[5];
  p.Wv      = (const float*)d_in[6];
  p.Wo      = (const float*)d_in[7];
  p.g1      = (const float*)d_in[8];
  p.b1      = (const float*)d_in[9];
  p.fW1     = (const float*)d_in[10];
  p.fb1     = (const float*)d_in[11];
  p.fW2     = (const float*)d_in[12];
  p.fb2     = (const float*)d_in[13];
  p.g2      = (const float*)d_in[14];
  p.b2      = (const float*)d_in[15];
  p.W_node  = (const float*)d_in[16];
  p.W_fixed = (const float*)d_in[17];
  p.W_step  = (const float*)d_in[18];
  p.W_out   = (const float*)d_in[19];
  p.Wc1     = (const float*)d_in[20];
  p.bc1     = (const float*)d_in[21];
  p.Wc2     = (const float*)d_in[22];
  p.bc2     = (const float*)d_in[23];
  p.out = (float*)d_out;

  kinit<<<512, 256, 0, stream>>>(p);
  for (int step = 0; step < 20; step++) {
    for (int l = 0; l < 3; l++) {
      ka1<<<dim3(512, 2), 256, 0, stream>>>(p, step, l);
      ka2<<<dim3(512, 2), 256, 0, stream>>>(p, step, l);
      kb<<<dim3(512, 2), 256, 0, stream>>>(p, step, l);
    }
    kd<<<512, 256, 0, stream>>>(p, step);
  }
}